// Round 8
// baseline (235.159 us; speedup 1.0000x reference)
//
#include <hip/hip_runtime.h>
#include <math.h>

#define S_LEN 1024
#define D_MOD 512
#define NH 8
#define DK 64
#define NB 8

typedef __attribute__((ext_vector_type(8))) short short8;     // 8 bf16
typedef __attribute__((ext_vector_type(4))) float floatx4;    // 16x16 acc
typedef __attribute__((ext_vector_type(16))) float floatx16;  // 32x32 acc

union U8 { ushort u[8]; short8 v; };

__device__ __forceinline__ ushort f2bf(float x) {
  unsigned u = __float_as_uint(x);
  unsigned r = (u + 0x7fffu + ((u >> 16) & 1u)) >> 16;  // RNE
  return (ushort)r;
}

#define SC1 0.18033688f  /* 0.125 * log2(e), folded into Qbf */

// ---------------------------------------------------------------------------
// Fused prep: y=0..2 cvt q/k/v fp32->bf16; y=3 mask bit-pack; y=4 wtrans x3.
// ---------------------------------------------------------------------------
__global__ __launch_bounds__(256) void prep_kern(
    const float* __restrict__ q, const float* __restrict__ k,
    const float* __restrict__ v, const int* __restrict__ smask,
    const float* __restrict__ W0, const float* __restrict__ W1,
    const float* __restrict__ W2,
    ushort* __restrict__ qo, ushort* __restrict__ ko, ushort* __restrict__ vo,
    unsigned long long* __restrict__ mb,
    ushort* __restrict__ T0, ushort* __restrict__ T1, ushort* __restrict__ T2)
{
  __shared__ __align__(16) ushort tile[64][72];
  const int y = blockIdx.y;
  const int t = threadIdx.x;
  if (y < 3) {
    const float* src = (y == 0) ? q : (y == 1) ? k : v;
    ushort* dst = (y == 0) ? qo : (y == 1) ? ko : vo;
    const int i = blockIdx.x * 256 + t;
    const float4 a = *((const float4*)src + i * 2);
    const float4 b = *((const float4*)src + i * 2 + 1);
    U8 o;
    o.u[0] = f2bf(a.x); o.u[1] = f2bf(a.y); o.u[2] = f2bf(a.z); o.u[3] = f2bf(a.w);
    o.u[4] = f2bf(b.x); o.u[5] = f2bf(b.y); o.u[6] = f2bf(b.z); o.u[7] = f2bf(b.w);
    *(short8*)(dst + (size_t)i * 8) = o.v;
  } else if (y == 3) {
    const int row = blockIdx.x * 4 + (t >> 6);
    const int lane = t & 63;
    const int* p = smask + (size_t)row * S_LEN;
    unsigned long long mine = 0;
#pragma unroll
    for (int r = 0; r < 16; ++r) {
      int m = p[r * 64 + lane];
      unsigned long long w = __ballot(m != 0);
      if (lane == r) mine = w;
    }
    if (lane < 16) mb[(size_t)row * 16 + lane] = mine;
  } else {
    if (blockIdx.x >= 192) return;
    const int z = blockIdx.x / 64;
    const int xy = blockIdx.x & 63;
    const float* W = (z == 0) ? W0 : (z == 1) ? W1 : W2;
    ushort* Wt = (z == 0) ? T0 : (z == 1) ? T1 : T2;
    const int n0 = (xy & 7) * 64;
    const int k0 = (xy >> 3) * 64;
    {
      const int r = t >> 2;
      const int c0 = (t & 3) * 16;
      const float* p = &W[(size_t)(k0 + r) * 512 + n0 + c0];
#pragma unroll
      for (int j = 0; j < 16; ++j) tile[r][c0 + j] = f2bf(p[j]);
    }
    __syncthreads();
    {
      const int c = t >> 2;
      const int kg = (t & 3) * 16;
      U8 lo, hi;
#pragma unroll
      for (int j = 0; j < 8; ++j) lo.u[j] = tile[kg + j][c];
#pragma unroll
      for (int j = 0; j < 8; ++j) hi.u[j] = tile[kg + 8 + j][c];
      ushort* qd = &Wt[(size_t)(n0 + c) * 512 + k0 + kg];
      *(short8*)qd = lo.v;
      *(short8*)(qd + 8) = hi.v;
    }
  }
}

// ---------------------------------------------------------------------------
// bf16 MFMA GEMM, double-buffered B-tile (64n x 64k, XOR-swizzled), A in regs
// with 2-deep prefetch. Block 128m x 64n, 4 waves. BK=64, 8 iters.
// z=0: bf16 out scaled by SC1 (attn Q pre-scale). z=1: bf16 out.
// z=2: write Vt [B,H,64,S] directly.
// ---------------------------------------------------------------------------
__global__ __launch_bounds__(256) void gemm_qkv_kern(
    const ushort* __restrict__ qr, const ushort* __restrict__ kr,
    const ushort* __restrict__ vr, const ushort* __restrict__ Wqt,
    const ushort* __restrict__ Wvt, const float* __restrict__ bq,
    const float* __restrict__ bv, ushort* __restrict__ Qo,
    ushort* __restrict__ Ko, ushort* __restrict__ VtO)
{
  __shared__ __align__(16) ushort Bl[2][64][64];

  const int z = blockIdx.z;
  const ushort* A = (z == 0) ? qr : (z == 1) ? kr : vr;
  const ushort* Wt = (z == 2) ? Wvt : Wqt;
  const float* bias = (z == 2) ? bv : bq;

  const int t = threadIdx.x;
  const int w = t >> 6;
  const int lane = t & 63;
  const int quad = lane >> 4;
  const int i16 = lane & 15;
  const int mbase = blockIdx.x * 128 + w * 32;
  const int nbase = blockIdx.y * 64;

  const int sr = t >> 2;
  const int slc = (t & 3) * 2;
  const int sp0 = ((slc ^ (sr & 7)) * 8);
  const int sp1 = (((slc + 1) ^ (sr & 7)) * 8);
  const ushort* Bg = Wt + (size_t)(nbase + sr) * 512 + (t & 3) * 16;
  const int xb = i16 & 7;

  const ushort* Ap = A + (size_t)(mbase + i16) * 512 + quad * 8;

  floatx4 acc[2][4];
#pragma unroll
  for (int mi = 0; mi < 2; ++mi)
#pragma unroll
    for (int ni = 0; ni < 4; ++ni) acc[mi][ni] = (floatx4)(0.f);

  short8 areg[3][2][2];
#pragma unroll
  for (int d = 0; d < 2; ++d)
#pragma unroll
    for (int mi = 0; mi < 2; ++mi)
#pragma unroll
      for (int kc = 0; kc < 2; ++kc)
        areg[d][mi][kc] = *(const short8*)(Ap + d * 64 + kc * 32 + mi * 16 * 512);

  {
    short8 b0 = *(const short8*)Bg;
    short8 b1 = *(const short8*)(Bg + 8);
    *(short8*)&Bl[0][sr][sp0] = b0;
    *(short8*)&Bl[0][sr][sp1] = b1;
    __syncthreads();
  }

#pragma unroll
  for (int kt = 0; kt < 8; ++kt) {
    const int cb = kt & 1;
    short8 nb0, nb1;
    if (kt < 7) {
      nb0 = *(const short8*)(Bg + (kt + 1) * 64);
      nb1 = *(const short8*)(Bg + (kt + 1) * 64 + 8);
    }
    if (kt < 6) {
#pragma unroll
      for (int mi = 0; mi < 2; ++mi)
#pragma unroll
        for (int kc = 0; kc < 2; ++kc)
          areg[(kt + 2) % 3][mi][kc] =
              *(const short8*)(Ap + (kt + 2) * 64 + kc * 32 + mi * 16 * 512);
    }
    short8 bf[2][4];
#pragma unroll
    for (int kc = 0; kc < 2; ++kc)
#pragma unroll
      for (int ni = 0; ni < 4; ++ni)
        bf[kc][ni] = *(const short8*)&Bl[cb][ni * 16 + i16][((kc * 4 + quad) ^ xb) * 8];
#pragma unroll
    for (int kc = 0; kc < 2; ++kc)
#pragma unroll
      for (int mi = 0; mi < 2; ++mi)
#pragma unroll
        for (int ni = 0; ni < 4; ++ni)
          acc[mi][ni] = __builtin_amdgcn_mfma_f32_16x16x32_bf16(
              areg[kt % 3][mi][kc], bf[kc][ni], acc[mi][ni], 0, 0, 0);
    if (kt < 7) {
      *(short8*)&Bl[cb ^ 1][sr][sp0] = nb0;
      *(short8*)&Bl[cb ^ 1][sr][sp1] = nb1;
      __syncthreads();
    }
  }

  float bv4[4];
#pragma unroll
  for (int ni = 0; ni < 4; ++ni) bv4[ni] = bias[nbase + ni * 16 + i16];

  if (z < 2) {
    ushort* C = (z == 0) ? Qo : Ko;
    const float sc = (z == 0) ? SC1 : 1.f;
#pragma unroll
    for (int mi = 0; mi < 2; ++mi)
#pragma unroll
      for (int ni = 0; ni < 4; ++ni)
#pragma unroll
        for (int r = 0; r < 4; ++r) {
          const int m = mbase + mi * 16 + quad * 4 + r;
          const int n = nbase + ni * 16 + i16;
          C[(size_t)m * 512 + n] = f2bf((acc[mi][ni][r] + bv4[ni]) * sc);
        }
  } else {
#pragma unroll
    for (int mi = 0; mi < 2; ++mi)
#pragma unroll
      for (int ni = 0; ni < 4; ++ni) {
        const int m = mbase + mi * 16 + quad * 4;
        const int b = m >> 10;
        const int s = m & 1023;
        const int n = nbase + ni * 16 + i16;
        const int h = n >> 6;
        const int c = n & 63;
        ushort4 pk;
        pk.x = f2bf(acc[mi][ni][0] + bv4[ni]);
        pk.y = f2bf(acc[mi][ni][1] + bv4[ni]);
        pk.z = f2bf(acc[mi][ni][2] + bv4[ni]);
        pk.w = f2bf(acc[mi][ni][3] + bv4[ni]);
        *(ushort4*)(VtO + (((size_t)b * NH + h) * DK + c) * S_LEN + s) = pk;
      }
  }
}

// ---------------------------------------------------------------------------
// Output GEMM: X = Obf @ Wot^T + bo + R (fp32 out).
// ---------------------------------------------------------------------------
__global__ __launch_bounds__(256) void gemm_out_kern(
    const ushort* __restrict__ A, const ushort* __restrict__ Wt,
    const float* __restrict__ bias, const float* __restrict__ R,
    float* __restrict__ X)
{
  __shared__ __align__(16) ushort Bl[2][64][64];

  const int t = threadIdx.x;
  const int w = t >> 6;
  const int lane = t & 63;
  const int quad = lane >> 4;
  const int i16 = lane & 15;
  const int mbase = blockIdx.x * 128 + w * 32;
  const int nbase = blockIdx.y * 64;

  const int sr = t >> 2;
  const int slc = (t & 3) * 2;
  const int sp0 = ((slc ^ (sr & 7)) * 8);
  const int sp1 = (((slc + 1) ^ (sr & 7)) * 8);
  const ushort* Bg = Wt + (size_t)(nbase + sr) * 512 + (t & 3) * 16;
  const int xb = i16 & 7;

  const ushort* Ap = A + (size_t)(mbase + i16) * 512 + quad * 8;

  floatx4 acc[2][4];
#pragma unroll
  for (int mi = 0; mi < 2; ++mi)
#pragma unroll
    for (int ni = 0; ni < 4; ++ni) acc[mi][ni] = (floatx4)(0.f);

  short8 areg[3][2][2];
#pragma unroll
  for (int d = 0; d < 2; ++d)
#pragma unroll
    for (int mi = 0; mi < 2; ++mi)
#pragma unroll
      for (int kc = 0; kc < 2; ++kc)
        areg[d][mi][kc] = *(const short8*)(Ap + d * 64 + kc * 32 + mi * 16 * 512);

  {
    short8 b0 = *(const short8*)Bg;
    short8 b1 = *(const short8*)(Bg + 8);
    *(short8*)&Bl[0][sr][sp0] = b0;
    *(short8*)&Bl[0][sr][sp1] = b1;
    __syncthreads();
  }

#pragma unroll
  for (int kt = 0; kt < 8; ++kt) {
    const int cb = kt & 1;
    short8 nb0, nb1;
    if (kt < 7) {
      nb0 = *(const short8*)(Bg + (kt + 1) * 64);
      nb1 = *(const short8*)(Bg + (kt + 1) * 64 + 8);
    }
    if (kt < 6) {
#pragma unroll
      for (int mi = 0; mi < 2; ++mi)
#pragma unroll
        for (int kc = 0; kc < 2; ++kc)
          areg[(kt + 2) % 3][mi][kc] =
              *(const short8*)(Ap + (kt + 2) * 64 + kc * 32 + mi * 16 * 512);
    }
    short8 bf[2][4];
#pragma unroll
    for (int kc = 0; kc < 2; ++kc)
#pragma unroll
      for (int ni = 0; ni < 4; ++ni)
        bf[kc][ni] = *(const short8*)&Bl[cb][ni * 16 + i16][((kc * 4 + quad) ^ xb) * 8];
#pragma unroll
    for (int kc = 0; kc < 2; ++kc)
#pragma unroll
      for (int mi = 0; mi < 2; ++mi)
#pragma unroll
        for (int ni = 0; ni < 4; ++ni)
          acc[mi][ni] = __builtin_amdgcn_mfma_f32_16x16x32_bf16(
              areg[kt % 3][mi][kc], bf[kc][ni], acc[mi][ni], 0, 0, 0);
    if (kt < 7) {
      *(short8*)&Bl[cb ^ 1][sr][sp0] = nb0;
      *(short8*)&Bl[cb ^ 1][sr][sp1] = nb1;
      __syncthreads();
    }
  }

  float bv4[4];
#pragma unroll
  for (int ni = 0; ni < 4; ++ni) bv4[ni] = bias[nbase + ni * 16 + i16];
#pragma unroll
  for (int mi = 0; mi < 2; ++mi)
#pragma unroll
    for (int ni = 0; ni < 4; ++ni)
#pragma unroll
      for (int r = 0; r < 4; ++r) {
        const int m = mbase + mi * 16 + quad * 4 + r;
        const int n = nbase + ni * 16 + i16;
        X[(size_t)m * 512 + n] = acc[mi][ni][r] + bv4[ni] + R[(size_t)m * 512 + n];
      }
}

// ---------------------------------------------------------------------------
// MFMA dual-score causal attention, LDS-bound redesign:
//  - scores via 32x32x16 MFMA computed TRANSPOSED (S^T = K.Q^T): A-frag = K
//    rows from LDS, B-frag = Q rows in regs. Halves score LDS reads + MFMA
//    instr count per q-row. D layout: col(lane&31)=q, row=(r&3)+8*(r>>2)+
//    4*(lane>>5)=key_local -> q is per-lane => 1 mask word/lane/iter, scalar l.
//  - PV via verified 16x16x32 (2 q-subtiles), P packed to LDS as b64 writes.
//  - block = 2 waves x 32q = 64 q rows; dbuf K/Kr/V (48KB) + P (8KB) = 56KB.
//  - grid (64 bh, 8 p), pairing p & 15-p -> uniform 17 iters; XCD-pinned.
// ---------------------------------------------------------------------------
__global__ __launch_bounds__(128) void attn_kern(
    const ushort* __restrict__ Qb, const ushort* __restrict__ Kb,
    const ushort* __restrict__ VtG, const ushort* __restrict__ qraw,
    const ushort* __restrict__ kraw,
    const unsigned long long* __restrict__ mbits,
    const float* __restrict__ gammas, ushort* __restrict__ Obf)
{
  __shared__ __align__(16) ushort Kp[2][64][64];
  __shared__ __align__(16) ushort Kr[2][64][64];
  __shared__ __align__(16) ushort Vc[2][64][64];
  __shared__ __align__(16) ushort Pl[2][32][64];

  const int t = threadIdx.x;
  const int w = t >> 6;               // wave 0/1
  const int lane = t & 63;
  const int l31 = lane & 31;
  const int lh = lane >> 5;           // half
  const int quad = (lane >> 4) & 3;
  const int i16 = lane & 15;
  const int bh = blockIdx.x;
  const int b = bh >> 3;
  const int h = bh & 7;
  const int p = blockIdx.y;

  const float gam = gammas[h];
  float te = __expf(-log1pf(__expf(gam)));
  te = fminf(fmaxf(te, 1e-5f), 1e5f);
  const float c2 = te * 0.044194173824159216f * 1.44269504f;

  // staging geometry (128 threads): rows rr4+16u, u=0..3
  const int rr4 = t >> 3;             // 0..15
  const int lc = t & 7;
  const int pc = ((lc ^ (rr4 & 7)) * 8);
  const ushort* kpgB = Kb + ((size_t)b * S_LEN + rr4) * D_MOD + h * DK + lc * 8;
  const ushort* krgB = kraw + ((size_t)b * S_LEN + rr4) * D_MOD + h * DK + lc * 8;
  const ushort* vgB  = VtG + ((size_t)bh * DK + rr4) * S_LEN + lc * 8;

#pragma unroll
  for (int seg = 0; seg < 2; ++seg) {
    const int qt = seg ? (15 - p) : p;
    const int qbase = qt * 64 + w * 32;
    const int qg = qbase + l31;       // this lane's q row (cols of S^T)

    // Q fragments as B^T rows: lane holds Q[q=l31][d = ds*16 + lh*8 + j]
    short8 Qp[4], Qr[4];
    {
      const ushort* qp = Qb + ((size_t)b * S_LEN + qg) * D_MOD + h * DK + lh * 8;
      const ushort* qq = qraw + ((size_t)b * S_LEN + qg) * D_MOD + h * DK + lh * 8;
#pragma unroll
      for (int ds = 0; ds < 4; ++ds) {
        Qp[ds] = *(const short8*)(qp + ds * 16);
        Qr[ds] = *(const short8*)(qq + ds * 16);
      }
    }
    const unsigned long long* mrow = mbits + ((size_t)b * S_LEN + qg) * 16;

    floatx4 Oacc[2][4];
#pragma unroll
    for (int sub = 0; sub < 2; ++sub)
#pragma unroll
      for (int t4 = 0; t4 < 4; ++t4) Oacc[sub][t4] = (floatx4)(0.f);
    float l_run = 0.f;

    const int nit = qt + 1;

    // prologue: stage tile 0 into buffer 0
    {
      short8 kv[4], rv[4], vv[4];
#pragma unroll
      for (int u = 0; u < 4; ++u) {
        kv[u] = *(const short8*)(kpgB + (size_t)(16 * u) * D_MOD);
        rv[u] = *(const short8*)(krgB + (size_t)(16 * u) * D_MOD);
        vv[u] = *(const short8*)(vgB + (size_t)(16 * u) * S_LEN);
      }
      __syncthreads();  // prior seg readers done
#pragma unroll
      for (int u = 0; u < 4; ++u) {
        *(short8*)&Kp[0][rr4 + 16 * u][pc] = kv[u];
        *(short8*)&Kr[0][rr4 + 16 * u][pc] = rv[u];
        *(short8*)&Vc[0][rr4 + 16 * u][pc] = vv[u];
      }
      __syncthreads();
    }

    for (int kt = 0; kt < nit; ++kt) {
      const int cb = kt & 1;
      const bool havenext = (kt + 1 < nit);
      const bool diag = (kt == qt);
      const int k0 = kt * 64;

      short8 nk[4], nr[4], nv[4];
      if (havenext) {
        const size_t ko = (size_t)(k0 + 64);
#pragma unroll
        for (int u = 0; u < 4; ++u) {
          nk[u] = *(const short8*)(kpgB + (ko + 16 * u) * D_MOD);
          nr[u] = *(const short8*)(krgB + (ko + 16 * u) * D_MOD);
          nv[u] = *(const short8*)(vgB + ko + (size_t)(16 * u) * S_LEN);
        }
      }
      const unsigned long long mw = mrow[kt];
      const unsigned mwl = (unsigned)mw;
      const unsigned mwh = (unsigned)(mw >> 32);

      // ---- scores S^T: 16 MFMAs (32x32x16). A = K rows, B = Q rows ----
      floatx16 accp[2], accr[2];
#pragma unroll
      for (int ct = 0; ct < 2; ++ct) { accp[ct] = (floatx16)(0.f); accr[ct] = (floatx16)(0.f); }
      const int xk = l31 & 7;
#pragma unroll
      for (int ds = 0; ds < 4; ++ds) {
        const int co = ((ds * 2 + lh) ^ xk) * 8;
        short8 kpf0 = *(const short8*)&Kp[cb][l31][co];
        short8 kpf1 = *(const short8*)&Kp[cb][32 + l31][co];
        short8 krf0 = *(const short8*)&Kr[cb][l31][co];
        short8 krf1 = *(const short8*)&Kr[cb][32 + l31][co];
        accp[0] = __builtin_amdgcn_mfma_f32_32x32x16_bf16(kpf0, Qp[ds], accp[0], 0, 0, 0);
        accp[1] = __builtin_amdgcn_mfma_f32_32x32x16_bf16(kpf1, Qp[ds], accp[1], 0, 0, 0);
        accr[0] = __builtin_amdgcn_mfma_f32_32x32x16_bf16(krf0, Qr[ds], accr[0], 0, 0, 0);
        accr[1] = __builtin_amdgcn_mfma_f32_32x32x16_bf16(krf1, Qr[ds], accr[1], 0, 0, 0);
      }

      // ---- combine + exp2; P^T -> Pl[q][key] with packed b64 writes ----
#pragma unroll
      for (int ct = 0; ct < 2; ++ct) {
        const unsigned mh = ct ? mwh : mwl;
#pragma unroll
        for (int j = 0; j < 4; ++j) {
          float pv4[4];
#pragma unroll
          for (int rr = 0; rr < 4; ++rr) {
            const int r = j * 4 + rr;
            const int key_local = rr + 4 * lh + 8 * j;
            const float bitf = ((mh >> key_local) & 1u) ? c2 : 0.f;
            const float sv = accp[ct][r] + accr[ct][r] * bitf;
            float pv = __builtin_amdgcn_exp2f(sv);
            if (diag) {
              const int kg = k0 + ct * 32 + key_local;
              pv = (kg < qg) ? pv : 0.f;
            }
            l_run += pv;
            pv4[rr] = pv;
          }
          unsigned u0 = (__float_as_uint(pv4[1]) & 0xffff0000u) |
                        (__float_as_uint(pv4[0]) >> 16);
          unsigned u1 = (__float_as_uint(pv4[3]) & 0xffff0000u) |
                        (__float_as_uint(pv4[2]) >> 16);
          uint2 pk = make_uint2(u0, u1);
          *(uint2*)&Pl[w][l31][((ct * 4 + j) ^ xk) * 8 + 4 * lh] = pk;
        }
      }

      // ---- PV: 16 MFMAs (16x16x32). A = P rows, B^T = Vc rows (d) ----
#pragma unroll
      for (int sub = 0; sub < 2; ++sub)
#pragma unroll
        for (int s = 0; s < 2; ++s) {
          const int arow = sub * 16 + i16;
          short8 a = *(const short8*)&Pl[w][arow][((s * 4 + quad) ^ (i16 & 7)) * 8];
#pragma unroll
          for (int t4 = 0; t4 < 4; ++t4) {
            short8 bv8 = *(const short8*)&Vc[cb][t4 * 16 + i16][((s * 4 + quad) ^ (i16 & 7)) * 8];
            Oacc[sub][t4] = __builtin_amdgcn_mfma_f32_16x16x32_bf16(a, bv8, Oacc[sub][t4], 0, 0, 0);
          }
        }

      if (havenext) {
#pragma unroll
        for (int u = 0; u < 4; ++u) {
          *(short8*)&Kp[cb ^ 1][rr4 + 16 * u][pc] = nk[u];
          *(short8*)&Kr[cb ^ 1][rr4 + 16 * u][pc] = nr[u];
          *(short8*)&Vc[cb ^ 1][rr4 + 16 * u][pc] = nv[u];
        }
        __syncthreads();
      }
    }

    // ---- epilogue: l lives at lanes (q=l31, both halves); merge + bcast ----
    const float l_tot = l_run + __shfl_xor(l_run, 32);
#pragma unroll
    for (int sub = 0; sub < 2; ++sub)
#pragma unroll
      for (int r = 0; r < 4; ++r) {
        const int q_local = sub * 16 + quad * 4 + r;
        const float lq = __shfl(l_tot, q_local);
        const float inv = (lq > 0.f) ? 1.f / lq : 0.f;
        ushort* orow = Obf + ((size_t)b * S_LEN + qbase + q_local) * D_MOD + h * DK;
#pragma unroll
        for (int t4 = 0; t4 < 4; ++t4)
          orow[t4 * 16 + i16] = f2bf(Oacc[sub][t4][r] * inv);
      }
  }
}

// ---------------------------------------------------------------------------
// LayerNorm over D=512, one wave per row.
// ---------------------------------------------------------------------------
__global__ __launch_bounds__(256) void ln_kern(
    const float* __restrict__ X, const float* __restrict__ gw,
    const float* __restrict__ bw, float* __restrict__ out)
{
  const int row = blockIdx.x * 4 + (threadIdx.x >> 6);
  const int lane = threadIdx.x & 63;
  const int c = lane * 8;
  const float* xp = &X[(size_t)row * D_MOD + c];
  const float4 x0 = *(const float4*)xp;
  const float4 x1 = *(const float4*)(xp + 4);
  float xv[8] = {x0.x, x0.y, x0.z, x0.w, x1.x, x1.y, x1.z, x1.w};
  float sum = 0.f;
#pragma unroll
  for (int u = 0; u < 8; ++u) sum += xv[u];
#pragma unroll
  for (int off = 1; off < 64; off <<= 1) sum += __shfl_xor(sum, off, 64);
  const float mu = sum * (1.f / 512.f);
  float ss = 0.f;
#pragma unroll
  for (int u = 0; u < 8; ++u) { xv[u] -= mu; ss += xv[u] * xv[u]; }
#pragma unroll
  for (int off = 1; off < 64; off <<= 1) ss += __shfl_xor(ss, off, 64);
  const float rstd = rsqrtf(ss * (1.f / 512.f) + 1e-5f);
  const float4 g0 = *(const float4*)&gw[c];
  const float4 g1 = *(const float4*)&gw[c + 4];
  const float4 b0 = *(const float4*)&bw[c];
  const float4 b1 = *(const float4*)&bw[c + 4];
  float* op = &out[(size_t)row * D_MOD + c];
  *(float4*)op = make_float4(xv[0] * rstd * g0.x + b0.x,
                             xv[1] * rstd * g0.y + b0.y,
                             xv[2] * rstd * g0.z + b0.z,
                             xv[3] * rstd * g0.w + b0.w);
  *(float4*)(op + 4) = make_float4(xv[4] * rstd * g1.x + b1.x,
                                   xv[5] * rstd * g1.y + b1.y,
                                   xv[6] * rstd * g1.z + b1.z,
                                   xv[7] * rstd * g1.w + b1.w);
}

// ---------------------------------------------------------------------------
extern "C" void kernel_launch(void* const* d_in, const int* in_sizes, int n_in,
                              void* d_out, int out_size, void* d_ws, size_t ws_size,
                              hipStream_t stream)
{
  const float* q_in  = (const float*)d_in[0];
  const float* k_in  = (const float*)d_in[1];
  const float* v_in  = (const float*)d_in[2];
  const int*   smask = (const int*)d_in[3];
  const float* Wq = (const float*)d_in[4];
  const float* bq = (const float*)d_in[5];
  const float* Wv = (const float*)d_in[6];
  const float* bv = (const float*)d_in[7];
  const float* Wo = (const float*)d_in[8];
  const float* bo = (const float*)d_in[9];
  const float* gammas = (const float*)d_in[10];
  const float* ln_g = (const float*)d_in[11];
  const float* ln_b = (const float*)d_in[12];
  float* out = (float*)d_out;

  char* ws = (char*)d_ws;
  const size_t BF = (size_t)NB * S_LEN * D_MOD * sizeof(ushort);  // 8 MiB
  ushort* qr  = (ushort*)(ws);                 // [0,8M)
  ushort* kr  = (ushort*)(ws + BF);            // [8M,16M)
  ushort* vr  = (ushort*)(ws + 2 * BF);        // [16M,24M); Obf overlays
  ushort* Obf = (ushort*)(ws + 2 * BF);
  ushort* Qbf = (ushort*)(ws + 3 * BF);        // [24M,32M)
  ushort* Kbf = (ushort*)(ws + 4 * BF);        // [32M,40M)
  ushort* Vt  = (ushort*)(ws + 5 * BF);        // [40M,48M)
  unsigned long long* mbits = (unsigned long long*)(ws + 6 * BF);      // 1 MiB
  ushort* Wqt = (ushort*)(ws + 6 * BF + (1 << 20));                    // 512 KiB
  ushort* Wvt = Wqt + 512 * 512;
  ushort* Wot = Wvt + 512 * 512;
  float*  X   = (float*)ws;                    // overlays qr+kr (dead by then)

  const dim3 tb(256);

  prep_kern<<<dim3(2048, 5), tb, 0, stream>>>(q_in, k_in, v_in, smask,
                                              Wq, Wv, Wo,
                                              qr, kr, vr, mbits,
                                              Wqt, Wvt, Wot);

  gemm_qkv_kern<<<dim3(64, 8, 3), tb, 0, stream>>>(qr, kr, vr, Wqt, Wvt,
                                                   bq, bv, Qbf, Kbf, Vt);

  attn_kern<<<dim3(64, 8), dim3(128), 0, stream>>>(Qbf, Kbf, Vt, qr, kr, mbits,
                                                   gammas, Obf);

  gemm_out_kern<<<dim3(64, 8), tb, 0, stream>>>(Obf, Wot, bo, q_in, X);
  ln_kern<<<2048, tb, 0, stream>>>(X, ln_g, ln_b, out);
}